// Round 1
// baseline (666.544 us; speedup 1.0000x reference)
//
#include <hip/hip_runtime.h>
#include <math.h>

// Paired Windows Attention — MI355X
// Pipeline: pool(gather+maxpool) -> window attention -> trilinear scatter.
//
// Constants from reference:
//   GROUP=1, HEADS=2, NUM_BSWIN=4, C=8, BIG={3,6,12,24}, SMALL={1,2,4,8},
//   NWIN=3, L=27. Input (4,64,48,48,48) f32. N per scale: 4096,512,64,8
//   (total 4680). Channel c_in = c_out = scale*16 + head*8 + c.

#define NTOT 4680
#define NWINDOWS_TOTAL 37440   // 4*2*4680
#define GATHER_ELEMS 8087040   // 37440*216

// ---------------------------------------------------------------------------
// Pool kernel: one thread per pooled output cell (per tensor q/k/v).
// Thread order (fastest->slowest): ld(3), nd(Nc), lw(3), nw(Nc), lh(3),
// nh(Nc), c(8), hd(2), b(4), tensor(3)  => waves sweep contiguous x.
// ---------------------------------------------------------------------------
template<int SW>
__global__ void pool_kernel(const float* __restrict__ q,
                            const float* __restrict__ k,
                            const float* __restrict__ v,
                            float* __restrict__ qg,
                            float* __restrict__ kg,
                            float* __restrict__ vg,
                            int scale, int Nc, int noff, unsigned int total)
{
    unsigned int tid = blockIdx.x * blockDim.x + threadIdx.x;
    if (tid >= total) return;
    const int BW = SW * 3;

    int ld = tid % 3;  tid /= 3;
    int nd = tid % Nc; tid /= Nc;
    int lw = tid % 3;  tid /= 3;
    int nw = tid % Nc; tid /= Nc;
    int lh = tid % 3;  tid /= 3;
    int nh = tid % Nc; tid /= Nc;
    int c  = tid % 8;  tid /= 8;
    int hd = tid % 2;  tid /= 2;
    int b  = tid % 4;  tid /= 4;
    int t  = (int)tid;

    const float* src = (t == 0) ? q : (t == 1) ? k : v;
    float*       dst = (t == 0) ? qg : (t == 1) ? kg : vg;

    int ch = scale * 16 + hd * 8 + c;
    int z0 = nh * BW + lh * SW;
    int y0 = nw * BW + lw * SW;
    int x0 = nd * BW + ld * SW;

    const float* base = src + ((((b * 64 + ch) * 48 + z0) * 48 + y0) * 48 + x0);

    float m = -INFINITY;
    #pragma unroll
    for (int dz = 0; dz < SW; dz++) {
        #pragma unroll
        for (int dy = 0; dy < SW; dy++) {
            const float* p = base + (dz * 48 + dy) * 48;
            #pragma unroll
            for (int dx = 0; dx < SW; dx++) m = fmaxf(m, p[dx]);
        }
    }

    int n = (nh * Nc + nw) * Nc + nd + noff;
    int l = (lh * 3 + lw) * 3 + ld;
    dst[(((b * 2 + hd) * NTOT + n) * 27 + l) * 8 + c] = m;
}

// ---------------------------------------------------------------------------
// Attention kernel: 256 threads = 8 windows x 32 lanes (27 active rows each).
// K,V staged in LDS. Scores in registers (fully unrolled).
// weights = softmax(scores/sqrt(8)) + rel_bias(m,n);  attn = weights @ V.
// attn overwrites qg in place (each thread only touches its own q row).
// ---------------------------------------------------------------------------
__global__ void attn_kernel(float* qg,                      // read q, write attn (aliased)
                            const float* __restrict__ kg,
                            const float* __restrict__ vg,
                            const float* __restrict__ rpb)  // (125, 2)
{
    __shared__ float ks[8][216];
    __shared__ float vs[8][216];
    __shared__ float tbl[250];

    int tid = threadIdx.x;
    int wbase = blockIdx.x * 8;

    for (int i = tid; i < 250; i += 256) tbl[i] = rpb[i];
    for (int i = tid; i < 8 * 216; i += 256) {
        int w = i / 216, r = i % 216;
        int g = (wbase + w) * 216 + r;
        ks[w][r] = kg[g];
        vs[w][r] = vg[g];
    }
    __syncthreads();

    int widx = tid >> 5;        // window within block
    int m    = tid & 31;        // query row
    if (m >= 27) return;

    int w  = wbase + widx;
    int hd = (w / NTOT) & 1;

    float qr[8];
    #pragma unroll
    for (int c = 0; c < 8; c++) qr[c] = qg[w * 216 + m * 8 + c];

    const float inv_scale = 0.35355339059327373f; // 1/sqrt(8)
    float s[27];
    float mx = -INFINITY;
    #pragma unroll
    for (int n = 0; n < 27; n++) {
        float acc = 0.f;
        #pragma unroll
        for (int c = 0; c < 8; c++) acc += qr[c] * ks[widx][n * 8 + c];
        acc *= inv_scale;
        s[n] = acc;
        mx = fmaxf(mx, acc);
    }
    float sum = 0.f;
    #pragma unroll
    for (int n = 0; n < 27; n++) { s[n] = expf(s[n] - mx); sum += s[n]; }
    float inv = 1.f / sum;

    int mz = m / 9, my = (m / 3) % 3, mxx = m % 3;

    float acc[8];
    #pragma unroll
    for (int c = 0; c < 8; c++) acc[c] = 0.f;
    #pragma unroll
    for (int n = 0; n < 27; n++) {
        int nz = n / 9, ny = (n / 3) % 3, nx = n % 3;
        int idx = ((mz - nz + 2) * 5 + (my - ny + 2)) * 5 + (mxx - nx + 2);
        float wgt = s[n] * inv + tbl[idx * 2 + hd];
        #pragma unroll
        for (int c = 0; c < 8; c++) acc[c] += wgt * vs[widx][n * 8 + c];
    }
    #pragma unroll
    for (int c = 0; c < 8; c++) qg[w * 216 + m * 8 + c] = acc[c];
}

// ---------------------------------------------------------------------------
// Scatter kernel: one thread per output element (x fastest -> coalesced
// writes). Trilinear (align-corners) interp from the window's 3x3x3 cells.
// ---------------------------------------------------------------------------
__global__ void scatter_kernel(const float* __restrict__ attn,
                               float* __restrict__ out)
{
    const unsigned int total = 28311552u; // 4*64*48*48*48
    unsigned int tid = blockIdx.x * blockDim.x + threadIdx.x;
    if (tid >= total) return;

    int x  = tid % 48; unsigned int r = tid / 48;
    int y  = r % 48; r /= 48;
    int z  = r % 48; r /= 48;
    int co = r % 64; r /= 64;
    int b  = (int)r;

    int i  = co >> 4;          // scale
    int hd = (co >> 3) & 1;
    int c  = co & 7;

    const int bws[4]  = {3, 6, 12, 24};
    const int ncs[4]  = {16, 8, 4, 2};
    const int noff[4] = {0, 4096, 4608, 4672};
    const float stt[4] = {1.0f, 2.0f / 5.0f, 2.0f / 11.0f, 2.0f / 23.0f};

    int bw = bws[i];
    int Nc = ncs[i];
    float st = stt[i];

    int nh = z / bw, pz = z - nh * bw;
    int nw = y / bw, py = y - nw * bw;
    int nd = x / bw, px = x - nd * bw;
    int n  = (nh * Nc + nw) * Nc + nd + noff[i];

    float fz = pz * st; int z0 = (int)fz; if (z0 > 2) z0 = 2; float wz = fz - z0; int z1 = min(z0 + 1, 2);
    float fy = py * st; int y0 = (int)fy; if (y0 > 2) y0 = 2; float wy = fy - y0; int y1 = min(y0 + 1, 2);
    float fx = px * st; int x0 = (int)fx; if (x0 > 2) x0 = 2; float wx = fx - x0; int x1 = min(x0 + 1, 2);

    const float* a = attn + ((b * 2 + hd) * NTOT + n) * 216 + c;
    #define AT(iz, iy, ix) a[(((iz) * 3 + (iy)) * 3 + (ix)) * 8]

    float c00 = AT(z0, y0, x0) * (1.f - wx) + AT(z0, y0, x1) * wx;
    float c01 = AT(z0, y1, x0) * (1.f - wx) + AT(z0, y1, x1) * wx;
    float c10 = AT(z1, y0, x0) * (1.f - wx) + AT(z1, y0, x1) * wx;
    float c11 = AT(z1, y1, x0) * (1.f - wx) + AT(z1, y1, x1) * wx;
    float c0  = c00 * (1.f - wy) + c01 * wy;
    float c1  = c10 * (1.f - wy) + c11 * wy;
    out[tid]  = c0 * (1.f - wz) + c1 * wz;
    #undef AT
}

// ---------------------------------------------------------------------------
extern "C" void kernel_launch(void* const* d_in, const int* in_sizes, int n_in,
                              void* d_out, int out_size, void* d_ws, size_t ws_size,
                              hipStream_t stream)
{
    const float* q   = (const float*)d_in[0];
    const float* k   = (const float*)d_in[1];
    const float* v   = (const float*)d_in[2];
    const float* rpb = (const float*)d_in[3];
    float* out = (float*)d_out;

    float* qg = (float*)d_ws;
    float* kg = qg + GATHER_ELEMS;
    float* vg = kg + GATHER_ELEMS;

    // Pool: total threads = 3 tensors * 4 b * 2 h * 8 c * windows * 27
    {
        unsigned int t0 = 3u * 4 * 2 * 8 * 4096 * 27; // 21,233,664
        pool_kernel<1><<<(t0 + 255) / 256, 256, 0, stream>>>(q, k, v, qg, kg, vg, 0, 16, 0, t0);
        unsigned int t1 = 3u * 4 * 2 * 8 * 512 * 27;  // 2,654,208
        pool_kernel<2><<<(t1 + 255) / 256, 256, 0, stream>>>(q, k, v, qg, kg, vg, 1, 8, 4096, t1);
        unsigned int t2 = 3u * 4 * 2 * 8 * 64 * 27;   // 331,776
        pool_kernel<4><<<(t2 + 255) / 256, 256, 0, stream>>>(q, k, v, qg, kg, vg, 2, 4, 4608, t2);
        unsigned int t3 = 3u * 4 * 2 * 8 * 8 * 27;    // 41,472
        pool_kernel<8><<<(t3 + 255) / 256, 256, 0, stream>>>(q, k, v, qg, kg, vg, 3, 2, 4672, t3);
    }

    // Attention: 8 windows per block, 37440 windows total.
    attn_kernel<<<NWINDOWS_TOTAL / 8, 256, 0, stream>>>(qg, kg, vg, rpb);

    // Scatter: one thread per output element.
    scatter_kernel<<<(28311552u + 255) / 256, 256, 0, stream>>>(qg, out);
}

// Round 2
// 593.424 us; speedup vs baseline: 1.1232x; 1.1232x over previous
//
#include <hip/hip_runtime.h>
#include <math.h>

// Paired Windows Attention — MI355X
// Pipeline: pool(gather+maxpool) -> window attention -> trilinear scatter.
// All three stages merged per-stage into single kernels with compile-time
// per-scale constants (no runtime divides, no scratch arrays).
//
// Constants: GROUP=1, HEADS=2, NUM_BSWIN=4, C=8, BIG={3,6,12,24},
// SMALL={1,2,4,8}, NWIN=3, L=27. Input (4,64,48,48,48) f32.
// Windows per scale: 4096,512,64,8 (total 4680). ch = scale*16 + hd*8 + c.

#define NTOT 4680
#define NWINDOWS_TOTAL 37440   // 4*2*4680
#define GATHER_ELEMS 8087040   // 37440*216

// ---------------------------------------------------------------------------
// Pool: one thread per pooled output cell (per tensor q/k/v).
// Thread order (fastest->slowest): c(8), ld(3), nd(NC), lw(3), nw(NC),
// lh(3), nh(NC), hd(2), b(4), tensor(3).
//   reads : per-channel contiguous SW-float spans (vectorized)
//   writes: 24 contiguous floats per (c,ld) lane group -> 96B chunks
// ---------------------------------------------------------------------------
template<int SW, int NC, int NOFF, int SCALE>
__device__ __forceinline__ void pool_impl(const float* __restrict__ q,
                                          const float* __restrict__ k,
                                          const float* __restrict__ v,
                                          float* __restrict__ qg,
                                          float* __restrict__ kg,
                                          float* __restrict__ vg,
                                          unsigned int tid)
{
    const int BW = SW * 3;
    int c  = tid % 8;  tid /= 8;
    int ld = tid % 3;  tid /= 3;
    int nd = tid % NC; tid /= NC;
    int lw = tid % 3;  tid /= 3;
    int nw = tid % NC; tid /= NC;
    int lh = tid % 3;  tid /= 3;
    int nh = tid % NC; tid /= NC;
    int hd = tid % 2;  tid /= 2;
    int b  = tid % 2;  tid /= 2;   // b in [0,4): split 2x2 to keep mods cheap
    b += (int)(tid % 2) * 2;       // (tid now has b-high + tensor)
    int t  = (int)(tid / 2);

    const float* src = (t == 0) ? q : (t == 1) ? k : v;
    float*       dst = (t == 0) ? qg : (t == 1) ? kg : vg;

    int ch = SCALE * 16 + hd * 8 + c;
    int z0 = nh * BW + lh * SW;
    int y0 = nw * BW + lw * SW;
    int x0 = nd * BW + ld * SW;

    const float* base = src + ((((b * 64 + ch) * 48 + z0) * 48 + y0) * 48 + x0);

    float m;
    if constexpr (SW == 1) {
        m = base[0];
    } else if constexpr (SW == 2) {
        m = -INFINITY;
        #pragma unroll
        for (int dz = 0; dz < 2; dz++) {
            #pragma unroll
            for (int dy = 0; dy < 2; dy++) {
                float2 p = *(const float2*)(base + (dz * 48 + dy) * 48);
                m = fmaxf(m, fmaxf(p.x, p.y));
            }
        }
    } else {
        m = -INFINITY;
        #pragma unroll
        for (int dz = 0; dz < SW; dz++) {
            #pragma unroll
            for (int dy = 0; dy < SW; dy++) {
                #pragma unroll
                for (int dx = 0; dx < SW; dx += 4) {
                    float4 p = *(const float4*)(base + (dz * 48 + dy) * 48 + dx);
                    m = fmaxf(m, fmaxf(fmaxf(p.x, p.y), fmaxf(p.z, p.w)));
                }
            }
        }
    }

    int n = (nh * NC + nw) * NC + nd + NOFF;
    int l = (lh * 3 + lw) * 3 + ld;
    dst[(((b * 2 + hd) * NTOT + n) * 27 + l) * 8 + c] = m;
}

// per-scale thread counts are exact multiples of 256 -> no tail guards
#define PB0 82944u   // 21233664/256  (scale 0)
#define PB1 93312u   // +10368       (scale 1)
#define PB2 94608u   // +1296        (scale 2)
#define PB3 94770u   // +162         (scale 3)

__global__ void pool_all(const float* __restrict__ q,
                         const float* __restrict__ k,
                         const float* __restrict__ v,
                         float* __restrict__ qg,
                         float* __restrict__ kg,
                         float* __restrict__ vg)
{
    unsigned int bid = blockIdx.x;
    if (bid < PB0) {
        pool_impl<1, 16, 0, 0>(q, k, v, qg, kg, vg, bid * 256 + threadIdx.x);
    } else if (bid < PB1) {
        pool_impl<2, 8, 4096, 1>(q, k, v, qg, kg, vg, (bid - PB0) * 256 + threadIdx.x);
    } else if (bid < PB2) {
        pool_impl<4, 4, 4608, 2>(q, k, v, qg, kg, vg, (bid - PB1) * 256 + threadIdx.x);
    } else {
        pool_impl<8, 2, 4672, 3>(q, k, v, qg, kg, vg, (bid - PB2) * 256 + threadIdx.x);
    }
}

// ---------------------------------------------------------------------------
// Attention: 256 threads = 8 windows x 32 lanes (27 active rows each).
// K,V staged in LDS as float4; scores in registers (fully unrolled).
// weights = softmax(scores/sqrt(8)) + rel_bias(m,n);  attn = weights @ V.
// attn overwrites qg in place (each thread only touches its own q row).
// ---------------------------------------------------------------------------
__global__ void attn_kernel(float* qg,                      // read q, write attn (aliased)
                            const float* __restrict__ kg,
                            const float* __restrict__ vg,
                            const float* __restrict__ rpb)  // (125, 2)
{
    __shared__ float4 ks[8][54];
    __shared__ float4 vs[8][54];
    __shared__ float tbl[250];

    int tid = threadIdx.x;
    int wbase = blockIdx.x * 8;

    for (int i = tid; i < 250; i += 256) tbl[i] = rpb[i];
    {
        const float4* kg4 = (const float4*)kg + (size_t)wbase * 54;
        const float4* vg4 = (const float4*)vg + (size_t)wbase * 54;
        float4* ksf = (float4*)ks;
        float4* vsf = (float4*)vs;
        for (int i = tid; i < 432; i += 256) {
            ksf[i] = kg4[i];
            vsf[i] = vg4[i];
        }
    }
    __syncthreads();

    int widx = tid >> 5;        // window within block
    int m    = tid & 31;        // query row
    if (m >= 27) return;

    int w  = wbase + widx;
    int hd = (w / NTOT) & 1;

    float4 q0 = *(const float4*)(qg + (size_t)w * 216 + m * 8);
    float4 q1 = *(const float4*)(qg + (size_t)w * 216 + m * 8 + 4);

    const float inv_scale = 0.35355339059327373f; // 1/sqrt(8)
    float s[27];
    float mx = -INFINITY;
    #pragma unroll
    for (int n = 0; n < 27; n++) {
        float4 k0 = ks[widx][n * 2];
        float4 k1 = ks[widx][n * 2 + 1];
        float acc = q0.x * k0.x + q0.y * k0.y + q0.z * k0.z + q0.w * k0.w
                  + q1.x * k1.x + q1.y * k1.y + q1.z * k1.z + q1.w * k1.w;
        acc *= inv_scale;
        s[n] = acc;
        mx = fmaxf(mx, acc);
    }
    float sum = 0.f;
    #pragma unroll
    for (int n = 0; n < 27; n++) { s[n] = __expf(s[n] - mx); sum += s[n]; }
    float inv = 1.f / sum;

    // bias index: idx = mbase - nconst, nconst compile-time per unroll iter
    int mz = m / 9, my = (m / 3) % 3, mxx = m % 3;
    int mbase = ((mz + 2) * 5 + (my + 2)) * 5 + (mxx + 2);

    float4 a0 = make_float4(0.f, 0.f, 0.f, 0.f);
    float4 a1 = make_float4(0.f, 0.f, 0.f, 0.f);
    #pragma unroll
    for (int n = 0; n < 27; n++) {
        const int nz = n / 9, ny = (n / 3) % 3, nx = n % 3;
        const int nconst = (nz * 5 + ny) * 5 + nx;
        float wgt = s[n] * inv + tbl[(mbase - nconst) * 2 + hd];
        float4 v0 = vs[widx][n * 2];
        float4 v1 = vs[widx][n * 2 + 1];
        a0.x += wgt * v0.x; a0.y += wgt * v0.y; a0.z += wgt * v0.z; a0.w += wgt * v0.w;
        a1.x += wgt * v1.x; a1.y += wgt * v1.y; a1.z += wgt * v1.z; a1.w += wgt * v1.w;
    }
    *(float4*)(qg + (size_t)w * 216 + m * 8)     = a0;
    *(float4*)(qg + (size_t)w * 216 + m * 8 + 4) = a1;
}

// ---------------------------------------------------------------------------
// Scatter: 4 outputs (one float4) per thread along x. Per-scale template:
// compile-time bw/Nc/noff/step -> magic-mul divides, no scratch.
// Scale 0 (bw=3) is the identity map: direct copy, no interpolation.
// ---------------------------------------------------------------------------
template<int SCALE>
__device__ __forceinline__ void scatter_impl(const float* __restrict__ attn,
                                             float* __restrict__ out,
                                             unsigned int tid)
{
    constexpr int BW   = (SCALE == 0) ? 3 : (SCALE == 1) ? 6 : (SCALE == 2) ? 12 : 24;
    constexpr int NC   = 16 >> SCALE;
    constexpr int NOFF = (SCALE == 0) ? 0 : (SCALE == 1) ? 4096 : (SCALE == 2) ? 4608 : 4672;
    const float ST = 2.0f / (float)(BW - 1);

    int xq  = tid % 12; tid /= 12;
    int y   = tid % 48; tid /= 48;
    int z   = tid % 48; tid /= 48;
    int chi = tid % 16; tid /= 16;
    int b   = (int)tid;

    int hd = chi >> 3, c = chi & 7;

    int nh = z / BW, pz = z - nh * BW;
    int nw = y / BW, py = y - nw * BW;

    int z0 = 0, z1 = 0, y0 = 0, y1 = 0;
    float wz = 0.f, wy = 0.f;
    if constexpr (SCALE != 0) {
        float fz = pz * ST; z0 = (int)fz; if (z0 > 2) z0 = 2; wz = fz - z0; z1 = min(z0 + 1, 2);
        float fy = py * ST; y0 = (int)fy; if (y0 > 2) y0 = 2; wy = fy - y0; y1 = min(y0 + 1, 2);
    }

    float res[4];
    #pragma unroll
    for (int j = 0; j < 4; j++) {
        int x  = xq * 4 + j;
        int nd = x / BW, px = x - nd * BW;
        int n  = (nh * NC + nw) * NC + nd + NOFF;
        const float* a = attn + (((size_t)(b * 2 + hd) * NTOT + n) * 216) + c;
        if constexpr (SCALE == 0) {
            res[j] = a[((pz * 3 + py) * 3 + px) * 8];
        } else {
            float fx = px * ST; int x0 = (int)fx; if (x0 > 2) x0 = 2;
            float wx = fx - x0; int x1 = min(x0 + 1, 2);
            #define AT(iz, iy, ix) a[(((iz) * 3 + (iy)) * 3 + (ix)) * 8]
            float c00 = AT(z0, y0, x0) * (1.f - wx) + AT(z0, y0, x1) * wx;
            float c01 = AT(z0, y1, x0) * (1.f - wx) + AT(z0, y1, x1) * wx;
            float c10 = AT(z1, y0, x0) * (1.f - wx) + AT(z1, y0, x1) * wx;
            float c11 = AT(z1, y1, x0) * (1.f - wx) + AT(z1, y1, x1) * wx;
            float c0  = c00 * (1.f - wy) + c01 * wy;
            float c1  = c10 * (1.f - wy) + c11 * wy;
            res[j] = c0 * (1.f - wz) + c1 * wz;
            #undef AT
        }
    }

    size_t ob = ((((size_t)(b * 64 + SCALE * 16 + chi) * 48 + z) * 48 + y) * 48) + xq * 4;
    *(float4*)(out + ob) = make_float4(res[0], res[1], res[2], res[3]);
}

#define SBLK 6912u  // 1769472/256 per scale, exact

__global__ void scatter_all(const float* __restrict__ attn,
                            float* __restrict__ out)
{
    unsigned int bid = blockIdx.x;
    if (bid < SBLK) {
        scatter_impl<0>(attn, out, bid * 256 + threadIdx.x);
    } else if (bid < 2 * SBLK) {
        scatter_impl<1>(attn, out, (bid - SBLK) * 256 + threadIdx.x);
    } else if (bid < 3 * SBLK) {
        scatter_impl<2>(attn, out, (bid - 2 * SBLK) * 256 + threadIdx.x);
    } else {
        scatter_impl<3>(attn, out, (bid - 3 * SBLK) * 256 + threadIdx.x);
    }
}

// ---------------------------------------------------------------------------
extern "C" void kernel_launch(void* const* d_in, const int* in_sizes, int n_in,
                              void* d_out, int out_size, void* d_ws, size_t ws_size,
                              hipStream_t stream)
{
    const float* q   = (const float*)d_in[0];
    const float* k   = (const float*)d_in[1];
    const float* v   = (const float*)d_in[2];
    const float* rpb = (const float*)d_in[3];
    float* out = (float*)d_out;

    float* qg = (float*)d_ws;
    float* kg = qg + GATHER_ELEMS;
    float* vg = kg + GATHER_ELEMS;

    pool_all<<<PB3, 256, 0, stream>>>(q, k, v, qg, kg, vg);
    attn_kernel<<<NWINDOWS_TOTAL / 8, 256, 0, stream>>>(qg, kg, vg, rpb);
    scatter_all<<<4 * SBLK, 256, 0, stream>>>(qg, out);
}

// Round 3
// 570.076 us; speedup vs baseline: 1.1692x; 1.0410x over previous
//
#include <hip/hip_runtime.h>
#include <math.h>

// Paired Windows Attention — MI355X
// Pipeline: pool(gather+maxpool) -> window attention -> trilinear scatter.
//
// Constants: GROUP=1, HEADS=2, NUM_BSWIN=4, C=8, BIG={3,6,12,24},
// SMALL={1,2,4,8}, NWIN=3, L=27. Input (4,64,48,48,48) f32.
// Windows per scale: 4096,512,64,8 (total 4680). ch = scale*16 + hd*8 + c.

#define NTOT 4680
#define NWINDOWS_TOTAL 37440   // 4*2*4680
#define GATHER_ELEMS 8087040   // 37440*216

// ---------------------------------------------------------------------------
// Pool, scale 0 (SW=1): pure transpose-gather, LDS-staged.
// Block = (tensor, b, hd, z, yhalf): loads 8ch x 24y x 48x contiguous float4,
// stores window-ordered [n][l][c] in 288B contiguous runs.
// LDS granule = 4 floats (c-half for one (y,x)); XOR swizzle g^=(x>>2)&7
// (bijective: key bits of g untouched by XOR) caps ds_write conflicts ~8-way.
// ---------------------------------------------------------------------------
__global__ void pool0_kernel(const float* __restrict__ q,
                             const float* __restrict__ k,
                             const float* __restrict__ v,
                             float* __restrict__ qg,
                             float* __restrict__ kg,
                             float* __restrict__ vg)
{
    __shared__ float lds[9216];   // 2304 granules * 4 floats = 36.9 KB

    unsigned int bid = blockIdx.x;
    int yh = bid & 1;  bid >>= 1;
    int z  = bid % 48; bid /= 48;
    int hd = bid & 1;  bid >>= 1;
    int b  = bid & 3;  bid >>= 2;
    int t  = (int)bid;            // 0..2

    const float* src = (t == 0) ? q : (t == 1) ? k : v;
    float*       dst = (t == 0) ? qg : (t == 1) ? kg : vg;

    int tid = threadIdx.x;
    const float* gsrc = src + ((size_t)(b * 64 + hd * 8) * 48 + z) * 2304 + yh * 1152;

    // ---- load: 9 float4 per thread, fully coalesced ----
    #pragma unroll
    for (int j = 0; j < 9; j++) {
        int f  = tid + 256 * j;          // 0..2303
        int c  = f / 288;                // channel 0..7
        int r  = f - c * 288;
        int y  = r / 12;                 // 0..23
        int xq = r - y * 12;             // 0..11
        float4 val = *(const float4*)(gsrc + (size_t)c * 110592 + y * 48 + xq * 4);
        int key   = xq & 7;
        int gbase = (y * 48 + xq * 4) * 2 + (c >> 2);
        int csub  = c & 3;
        lds[((gbase + 0) ^ key) * 4 + csub] = val.x;
        lds[((gbase + 2) ^ key) * 4 + csub] = val.y;
        lds[((gbase + 4) ^ key) * 4 + csub] = val.z;
        lds[((gbase + 6) ^ key) * 4 + csub] = val.w;
    }
    __syncthreads();

    // ---- store: window-ordered, 288B contiguous runs ----
    int nh = z / 3, lh = z - nh * 3;
    int bh = b * 2 + hd;
    float4* dst4 = (float4*)dst;
    #pragma unroll
    for (int j = 0; j < 9; j++) {
        int cw     = tid + 256 * j;      // 0..2303
        int window = cw / 18;            // 0..127 = nw_loc*16 + nd
        int off    = cw - window * 18;   // (lw,ld,chalf), chalf fastest
        int chalf  = off & 1;
        int t2     = off >> 1;
        int ld     = t2 % 3;
        int lw     = t2 / 3;
        int nw_loc = window >> 4;
        int nd     = window & 15;
        int yl = nw_loc * 3 + lw;
        int x  = nd * 3 + ld;
        int g  = (yl * 48 + x) * 2 + chalf;
        int gs = g ^ ((x >> 2) & 7);
        float4 val = *(const float4*)&lds[gs * 4];
        int n = nh * 256 + (yh * 8 + nw_loc) * 16 + nd;
        dst4[((size_t)bh * NTOT + n) * 54 + lh * 18 + off] = val;
    }
}

// ---------------------------------------------------------------------------
// Pool, scales 1-3 (SW=2,4,8): one thread per pooled cell.
// Per-wave per-channel read granules are >=64B (x-spans contiguous).
// ---------------------------------------------------------------------------
template<int SW, int NC, int NOFF, int SCALE>
__device__ __forceinline__ void pool_impl(const float* __restrict__ q,
                                          const float* __restrict__ k,
                                          const float* __restrict__ v,
                                          float* __restrict__ qg,
                                          float* __restrict__ kg,
                                          float* __restrict__ vg,
                                          unsigned int tid)
{
    const int BW = SW * 3;
    int c  = tid % 8;  tid /= 8;
    int ld = tid % 3;  tid /= 3;
    int nd = tid % NC; tid /= NC;
    int lw = tid % 3;  tid /= 3;
    int nw = tid % NC; tid /= NC;
    int lh = tid % 3;  tid /= 3;
    int nh = tid % NC; tid /= NC;
    int hd = tid % 2;  tid /= 2;
    int b  = tid % 2;  tid /= 2;
    b += (int)(tid % 2) * 2;
    int t  = (int)(tid / 2);

    const float* src = (t == 0) ? q : (t == 1) ? k : v;
    float*       dst = (t == 0) ? qg : (t == 1) ? kg : vg;

    int ch = SCALE * 16 + hd * 8 + c;
    int z0 = nh * BW + lh * SW;
    int y0 = nw * BW + lw * SW;
    int x0 = nd * BW + ld * SW;

    const float* base = src + ((((b * 64 + ch) * 48 + z0) * 48 + y0) * 48 + x0);

    float m = -INFINITY;
    if constexpr (SW == 2) {
        #pragma unroll
        for (int dz = 0; dz < 2; dz++) {
            #pragma unroll
            for (int dy = 0; dy < 2; dy++) {
                float2 p = *(const float2*)(base + (dz * 48 + dy) * 48);
                m = fmaxf(m, fmaxf(p.x, p.y));
            }
        }
    } else {
        #pragma unroll
        for (int dz = 0; dz < SW; dz++) {
            #pragma unroll
            for (int dy = 0; dy < SW; dy++) {
                #pragma unroll
                for (int dx = 0; dx < SW; dx += 4) {
                    float4 p = *(const float4*)(base + (dz * 48 + dy) * 48 + dx);
                    m = fmaxf(m, fmaxf(fmaxf(p.x, p.y), fmaxf(p.z, p.w)));
                }
            }
        }
    }

    int n = (nh * NC + nw) * NC + nd + NOFF;
    int l = (lh * 3 + lw) * 3 + ld;
    dst[(((b * 2 + hd) * NTOT + n) * 27 + l) * 8 + c] = m;
}

// per-scale block counts (exact multiples of 256 threads)
#define RB1 10368u   // scale 1: 2654208/256
#define RB2 11664u   // +1296   (scale 2)
#define RB3 11826u   // +162    (scale 3)

__global__ void pool_rest(const float* __restrict__ q,
                          const float* __restrict__ k,
                          const float* __restrict__ v,
                          float* __restrict__ qg,
                          float* __restrict__ kg,
                          float* __restrict__ vg)
{
    unsigned int bid = blockIdx.x;
    if (bid < RB1) {
        pool_impl<2, 8, 4096, 1>(q, k, v, qg, kg, vg, bid * 256 + threadIdx.x);
    } else if (bid < RB2) {
        pool_impl<4, 4, 4608, 2>(q, k, v, qg, kg, vg, (bid - RB1) * 256 + threadIdx.x);
    } else {
        pool_impl<8, 2, 4672, 3>(q, k, v, qg, kg, vg, (bid - RB2) * 256 + threadIdx.x);
    }
}

// ---------------------------------------------------------------------------
// Attention: 256 threads = 8 windows x 32 lanes (27 active rows each).
// Q,K,V staged in LDS as float4 (coalesced); results written back into the
// q-tile, then one cooperative coalesced float4 store.
// weights = softmax(scores/sqrt(8)) + rel_bias(m,n);  attn = weights @ V.
// ---------------------------------------------------------------------------
__global__ void attn_kernel(float* qg,                      // read q, write attn (aliased)
                            const float* __restrict__ kg,
                            const float* __restrict__ vg,
                            const float* __restrict__ rpb)  // (125, 2)
{
    __shared__ float4 ks[432];   // [w8][54]
    __shared__ float4 vs[432];
    __shared__ float4 qs[432];
    __shared__ float tbl[250];

    int tid = threadIdx.x;
    int wbase = blockIdx.x * 8;
    int hd = (blockIdx.x / 585) & 1;   // 4680 = 8*585: blocks never straddle bh

    for (int i = tid; i < 250; i += 256) tbl[i] = rpb[i];
    {
        const float4* kg4 = (const float4*)kg + (size_t)wbase * 54;
        const float4* vg4 = (const float4*)vg + (size_t)wbase * 54;
        const float4* qg4 = (const float4*)qg + (size_t)wbase * 54;
        for (int i = tid; i < 432; i += 256) {
            ks[i] = kg4[i];
            vs[i] = vg4[i];
            qs[i] = qg4[i];
        }
    }
    __syncthreads();

    int widx = tid >> 5;        // window within block
    int m    = tid & 31;        // query row
    if (m < 27) {
        float4 q0 = qs[widx * 54 + m * 2];
        float4 q1 = qs[widx * 54 + m * 2 + 1];

        const float inv_scale = 0.35355339059327373f; // 1/sqrt(8)
        float s[27];
        float mx = -INFINITY;
        #pragma unroll
        for (int n = 0; n < 27; n++) {
            float4 k0 = ks[widx * 54 + n * 2];
            float4 k1 = ks[widx * 54 + n * 2 + 1];
            float acc = q0.x * k0.x + q0.y * k0.y + q0.z * k0.z + q0.w * k0.w
                      + q1.x * k1.x + q1.y * k1.y + q1.z * k1.z + q1.w * k1.w;
            acc *= inv_scale;
            s[n] = acc;
            mx = fmaxf(mx, acc);
        }
        float sum = 0.f;
        #pragma unroll
        for (int n = 0; n < 27; n++) { s[n] = __expf(s[n] - mx); sum += s[n]; }
        float inv = 1.f / sum;

        int mz = m / 9, my = (m / 3) % 3, mxx = m % 3;
        int mbase = ((mz + 2) * 5 + (my + 2)) * 5 + (mxx + 2);

        float4 a0 = make_float4(0.f, 0.f, 0.f, 0.f);
        float4 a1 = make_float4(0.f, 0.f, 0.f, 0.f);
        #pragma unroll
        for (int n = 0; n < 27; n++) {
            const int nz = n / 9, ny = (n / 3) % 3, nx = n % 3;
            const int nconst = (nz * 5 + ny) * 5 + nx;
            float wgt = s[n] * inv + tbl[(mbase - nconst) * 2 + hd];
            float4 v0 = vs[widx * 54 + n * 2];
            float4 v1 = vs[widx * 54 + n * 2 + 1];
            a0.x += wgt * v0.x; a0.y += wgt * v0.y; a0.z += wgt * v0.z; a0.w += wgt * v0.w;
            a1.x += wgt * v1.x; a1.y += wgt * v1.y; a1.z += wgt * v1.z; a1.w += wgt * v1.w;
        }
        // each lane overwrites only its own q row (already consumed)
        qs[widx * 54 + m * 2]     = a0;
        qs[widx * 54 + m * 2 + 1] = a1;
    }
    __syncthreads();

    float4* og4 = (float4*)qg + (size_t)wbase * 54;
    for (int i = tid; i < 432; i += 256) og4[i] = qs[i];
}

// ---------------------------------------------------------------------------
// Scatter: 4 outputs (one float4) per thread along x. Per-scale template:
// compile-time bw/Nc/noff/step. Scale 0 (bw=3) is the identity map.
// ---------------------------------------------------------------------------
template<int SCALE>
__device__ __forceinline__ void scatter_impl(const float* __restrict__ attn,
                                             float* __restrict__ out,
                                             unsigned int tid)
{
    constexpr int BW   = (SCALE == 0) ? 3 : (SCALE == 1) ? 6 : (SCALE == 2) ? 12 : 24;
    constexpr int NC   = 16 >> SCALE;
    constexpr int NOFF = (SCALE == 0) ? 0 : (SCALE == 1) ? 4096 : (SCALE == 2) ? 4608 : 4672;
    const float ST = 2.0f / (float)(BW - 1);

    int xq  = tid % 12; tid /= 12;
    int y   = tid % 48; tid /= 48;
    int z   = tid % 48; tid /= 48;
    int chi = tid % 16; tid /= 16;
    int b   = (int)tid;

    int hd = chi >> 3, c = chi & 7;

    int nh = z / BW, pz = z - nh * BW;
    int nw = y / BW, py = y - nw * BW;

    int z0 = 0, z1 = 0, y0 = 0, y1 = 0;
    float wz = 0.f, wy = 0.f;
    if constexpr (SCALE != 0) {
        float fz = pz * ST; z0 = (int)fz; if (z0 > 2) z0 = 2; wz = fz - z0; z1 = min(z0 + 1, 2);
        float fy = py * ST; y0 = (int)fy; if (y0 > 2) y0 = 2; wy = fy - y0; y1 = min(y0 + 1, 2);
    }

    float res[4];
    #pragma unroll
    for (int j = 0; j < 4; j++) {
        int x  = xq * 4 + j;
        int nd = x / BW, px = x - nd * BW;
        int n  = (nh * NC + nw) * NC + nd + NOFF;
        const float* a = attn + (((size_t)(b * 2 + hd) * NTOT + n) * 216) + c;
        if constexpr (SCALE == 0) {
            res[j] = a[((pz * 3 + py) * 3 + px) * 8];
        } else {
            float fx = px * ST; int x0 = (int)fx; if (x0 > 2) x0 = 2;
            float wx = fx - x0; int x1 = min(x0 + 1, 2);
            #define AT(iz, iy, ix) a[(((iz) * 3 + (iy)) * 3 + (ix)) * 8]
            float c00 = AT(z0, y0, x0) * (1.f - wx) + AT(z0, y0, x1) * wx;
            float c01 = AT(z0, y1, x0) * (1.f - wx) + AT(z0, y1, x1) * wx;
            float c10 = AT(z1, y0, x0) * (1.f - wx) + AT(z1, y0, x1) * wx;
            float c11 = AT(z1, y1, x0) * (1.f - wx) + AT(z1, y1, x1) * wx;
            float c0  = c00 * (1.f - wy) + c01 * wy;
            float c1  = c10 * (1.f - wy) + c11 * wy;
            res[j] = c0 * (1.f - wz) + c1 * wz;
            #undef AT
        }
    }

    size_t ob = ((((size_t)(b * 64 + SCALE * 16 + chi) * 48 + z) * 48 + y) * 48) + xq * 4;
    *(float4*)(out + ob) = make_float4(res[0], res[1], res[2], res[3]);
}

#define SBLK 6912u  // 1769472/256 per scale, exact

__global__ void scatter_all(const float* __restrict__ attn,
                            float* __restrict__ out)
{
    unsigned int bid = blockIdx.x;
    if (bid < SBLK) {
        scatter_impl<0>(attn, out, bid * 256 + threadIdx.x);
    } else if (bid < 2 * SBLK) {
        scatter_impl<1>(attn, out, (bid - SBLK) * 256 + threadIdx.x);
    } else if (bid < 3 * SBLK) {
        scatter_impl<2>(attn, out, (bid - 2 * SBLK) * 256 + threadIdx.x);
    } else {
        scatter_impl<3>(attn, out, (bid - 3 * SBLK) * 256 + threadIdx.x);
    }
}

// ---------------------------------------------------------------------------
extern "C" void kernel_launch(void* const* d_in, const int* in_sizes, int n_in,
                              void* d_out, int out_size, void* d_ws, size_t ws_size,
                              hipStream_t stream)
{
    const float* q   = (const float*)d_in[0];
    const float* k   = (const float*)d_in[1];
    const float* v   = (const float*)d_in[2];
    const float* rpb = (const float*)d_in[3];
    float* out = (float*)d_out;

    float* qg = (float*)d_ws;
    float* kg = qg + GATHER_ELEMS;
    float* vg = kg + GATHER_ELEMS;

    pool0_kernel<<<2304, 256, 0, stream>>>(q, k, v, qg, kg, vg);
    pool_rest<<<RB3, 256, 0, stream>>>(q, k, v, qg, kg, vg);
    attn_kernel<<<NWINDOWS_TOTAL / 8, 256, 0, stream>>>(qg, kg, vg, rpb);
    scatter_all<<<4 * SBLK, 256, 0, stream>>>(qg, out);
}

// Round 4
// 465.368 us; speedup vs baseline: 1.4323x; 1.2250x over previous
//
#include <hip/hip_runtime.h>
#include <math.h>

// Paired Windows Attention — MI355X
// Scales 0,1: fully fused pool+attention+scatter (one block per window-row,
//   no intermediate HBM traffic).
// Scales 2,3: pool -> attn -> scatter through a tiny (L2-resident) buffer.
//
// Constants: GROUP=1, HEADS=2, NUM_BSWIN=4, C=8, BIG={3,6,12,24},
// SMALL={1,2,4,8}, NWIN=3, L=27. Input (4,64,48,48,48) f32.
// Windows/scale: 4096,512,64,8 (tot 4680). ch = scale*16 + hd*8 + c.

#define NTOT 4680
#define GATHER_ELEMS 8087040   // 37440*216 (full-size indexing kept; only
                               // the scale-2/3 region is actually touched)

// ---------------------------------------------------------------------------
// Fused kernel, scales 0 and 1. Block = (bh, nh, nw) = one x-row of windows
// (16 windows for SW=1, 8 for SW=2), 512 threads.
// Phase 1: load+pool q,k,v region into LDS [w][l][c] (global reads = 576B runs)
// Phase 2: window attention (K/V LDS reads are wave-broadcasts, conflict-free)
// Phase 3: trilinear upsample straight to output (576/1152B coalesced runs)
// ---------------------------------------------------------------------------
template<int SW>
__device__ __forceinline__ void fused_body(const float* __restrict__ q,
                                           const float* __restrict__ k,
                                           const float* __restrict__ v,
                                           const float* __restrict__ rpb,
                                           float* __restrict__ out,
                                           unsigned int bid,
                                           float* qs, float* ks, float* vs,
                                           float* tbl)
{
    constexpr int SCALE = (SW == 1) ? 0 : 1;
    constexpr int NC    = (SW == 1) ? 16 : 8;   // windows along each axis
    constexpr int NWIN  = NC;                   // windows in this block
    int tid = threadIdx.x;

    int nw = bid % NC; bid /= NC;
    int nh = bid % NC; bid /= NC;
    int bh = (int)bid;                 // 0..7
    int b = bh >> 1, hd = bh & 1;
    int chb = SCALE * 16 + hd * 8;

    for (int i = tid; i < 250; i += 512) tbl[i] = rpb[i];

    // ---- phase 1: load (+pool) into LDS [w][l(27)][c(8)] ----
    if constexpr (SW == 1) {
        // identity pool: 2592 float4 (3 tensors x 8c x 3z x 3y x 12xq)
        for (int i = tid; i < 2592; i += 512) {
            int t = i / 864;
            int r = i - t * 864;
            int c = r / 108; r -= c * 108;
            int z = r / 36;  r -= z * 36;
            int y = r / 12;
            int xq = r - y * 12;
            const float* src = (t == 0) ? q : (t == 1) ? k : v;
            float* dst = (t == 0) ? qs : (t == 1) ? ks : vs;
            const float* p = src + (((size_t)(b * 64 + chb + c) * 48 + nh * 3 + z) * 48
                                    + nw * 3 + y) * 48 + xq * 4;
            float4 val = *(const float4*)p;
            float tmp[4] = {val.x, val.y, val.z, val.w};
            #pragma unroll
            for (int e = 0; e < 4; e++) {
                int x = xq * 4 + e;
                int w = x / 3, ld = x - w * 3;
                dst[(w * 27 + z * 9 + y * 3 + ld) * 8 + c] = tmp[e];
            }
        }
    } else {
        // 2x2x2 max-pool: 5184 cells (3t x 8c x 3lz x 3ly x 24 xcell)
        for (int i = tid; i < 5184; i += 512) {
            int t = i / 1728;
            int r = i - t * 1728;
            int c  = r / 216; r -= c * 216;
            int lz = r / 72;  r -= lz * 72;
            int ly = r / 24;
            int xc = r - ly * 24;
            const float* src = (t == 0) ? q : (t == 1) ? k : v;
            float* dst = (t == 0) ? qs : (t == 1) ? ks : vs;
            const float* base = src + (((size_t)(b * 64 + chb + c) * 48 + nh * 6 + lz * 2) * 48
                                       + nw * 6 + ly * 2) * 48 + xc * 2;
            float m = -INFINITY;
            #pragma unroll
            for (int dz = 0; dz < 2; dz++) {
                #pragma unroll
                for (int dy = 0; dy < 2; dy++) {
                    float2 p2 = *(const float2*)(base + (dz * 48 + dy) * 48);
                    m = fmaxf(m, fmaxf(p2.x, p2.y));
                }
            }
            int w = xc / 3, ld = xc - w * 3;
            dst[(w * 27 + lz * 9 + ly * 3 + ld) * 8 + c] = m;
        }
    }
    __syncthreads();

    // ---- phase 2: attention (results overwrite qs, each lane its own row) ----
    {
        int widx = tid >> 5, m = tid & 31;
        if (widx < NWIN && m < 27) {
            float4 q0 = *(float4*)&qs[(widx * 27 + m) * 8];
            float4 q1 = *(float4*)&qs[(widx * 27 + m) * 8 + 4];
            const float inv_scale = 0.35355339059327373f; // 1/sqrt(8)
            float s[27], mx = -INFINITY;
            #pragma unroll
            for (int n = 0; n < 27; n++) {
                float4 k0 = *(float4*)&ks[(widx * 27 + n) * 8];
                float4 k1 = *(float4*)&ks[(widx * 27 + n) * 8 + 4];
                float acc = q0.x * k0.x + q0.y * k0.y + q0.z * k0.z + q0.w * k0.w
                          + q1.x * k1.x + q1.y * k1.y + q1.z * k1.z + q1.w * k1.w;
                acc *= inv_scale;
                s[n] = acc; mx = fmaxf(mx, acc);
            }
            float sum = 0.f;
            #pragma unroll
            for (int n = 0; n < 27; n++) { s[n] = __expf(s[n] - mx); sum += s[n]; }
            float inv = 1.f / sum;

            int mz = m / 9, my = (m / 3) % 3, mxx = m % 3;
            int mbase = ((mz + 2) * 5 + (my + 2)) * 5 + (mxx + 2);

            float4 a0 = make_float4(0.f, 0.f, 0.f, 0.f);
            float4 a1 = make_float4(0.f, 0.f, 0.f, 0.f);
            #pragma unroll
            for (int n = 0; n < 27; n++) {
                const int nz = n / 9, ny = (n / 3) % 3, nx = n % 3;
                const int nconst = (nz * 5 + ny) * 5 + nx;
                float wgt = s[n] * inv + tbl[(mbase - nconst) * 2 + hd];
                float4 v0 = *(float4*)&vs[(widx * 27 + n) * 8];
                float4 v1 = *(float4*)&vs[(widx * 27 + n) * 8 + 4];
                a0.x += wgt * v0.x; a0.y += wgt * v0.y; a0.z += wgt * v0.z; a0.w += wgt * v0.w;
                a1.x += wgt * v1.x; a1.y += wgt * v1.y; a1.z += wgt * v1.z; a1.w += wgt * v1.w;
            }
            *(float4*)&qs[(widx * 27 + m) * 8]     = a0;
            *(float4*)&qs[(widx * 27 + m) * 8 + 4] = a1;
        }
    }
    __syncthreads();

    // ---- phase 3: upsample + store ----
    if constexpr (SW == 1) {
        // identity: 864 float4 (8c x 3zz x 3yy x 12xq)
        for (int i = tid; i < 864; i += 512) {
            int c = i / 108;
            int r = i - c * 108;
            int zz = r / 36; r -= zz * 36;
            int yy = r / 12;
            int xq = r - yy * 12;
            float res[4];
            #pragma unroll
            for (int e = 0; e < 4; e++) {
                int x = xq * 4 + e;
                int w = x / 3, ld = x - w * 3;
                res[e] = qs[(w * 27 + zz * 9 + yy * 3 + ld) * 8 + c];
            }
            float* po = out + (((size_t)(b * 64 + chb + c) * 48 + nh * 3 + zz) * 48
                               + nw * 3 + yy) * 48 + xq * 4;
            *(float4*)po = make_float4(res[0], res[1], res[2], res[3]);
        }
    } else {
        // trilinear: 3456 float4 (8c x 6zz x 6yy x 12xq), ST = 2/5
        const float ST = 2.0f / 5.0f;
        for (int i = tid; i < 3456; i += 512) {
            int c = i / 432;
            int r = i - c * 432;
            int zz = r / 72; r -= zz * 72;
            int yy = r / 12;
            int xq = r - yy * 12;
            float fz = zz * ST; int z0 = (int)fz; if (z0 > 2) z0 = 2;
            float wz = fz - z0; int z1 = min(z0 + 1, 2);
            float fy = yy * ST; int y0 = (int)fy; if (y0 > 2) y0 = 2;
            float wy = fy - y0; int y1 = min(y0 + 1, 2);
            float res[4];
            #pragma unroll
            for (int e = 0; e < 4; e++) {
                int x = xq * 4 + e;
                int w = x / 6, px = x - w * 6;
                float fx = px * ST; int x0 = (int)fx; if (x0 > 2) x0 = 2;
                float wx = fx - x0; int x1 = min(x0 + 1, 2);
                const float* a = &qs[w * 216 + c];
                #define AT(iz, iy, ix) a[(((iz) * 3 + (iy)) * 3 + (ix)) * 8]
                float c00 = AT(z0, y0, x0) * (1.f - wx) + AT(z0, y0, x1) * wx;
                float c01 = AT(z0, y1, x0) * (1.f - wx) + AT(z0, y1, x1) * wx;
                float c10 = AT(z1, y0, x0) * (1.f - wx) + AT(z1, y0, x1) * wx;
                float c11 = AT(z1, y1, x0) * (1.f - wx) + AT(z1, y1, x1) * wx;
                float c0  = c00 * (1.f - wy) + c01 * wy;
                float c1  = c10 * (1.f - wy) + c11 * wy;
                res[e] = c0 * (1.f - wz) + c1 * wz;
                #undef AT
            }
            float* po = out + (((size_t)(b * 64 + chb + c) * 48 + nh * 6 + zz) * 48
                               + nw * 6 + yy) * 48 + xq * 4;
            *(float4*)po = make_float4(res[0], res[1], res[2], res[3]);
        }
    }
}

__global__ __launch_bounds__(512)
void fused01_kernel(const float* __restrict__ q, const float* __restrict__ k,
                    const float* __restrict__ v, const float* __restrict__ rpb,
                    float* __restrict__ out)
{
    __shared__ __align__(16) float qs[3456];
    __shared__ __align__(16) float ks[3456];
    __shared__ __align__(16) float vs[3456];
    __shared__ float tbl[250];
    unsigned int bid = blockIdx.x;
    if (bid < 2048) fused_body<1>(q, k, v, rpb, out, bid, qs, ks, vs, tbl);
    else            fused_body<2>(q, k, v, rpb, out, bid - 2048, qs, ks, vs, tbl);
}

// ---------------------------------------------------------------------------
// Pool, scales 2-3: one thread per pooled cell; ld,nd fastest so per-wave
// per-channel-plane read granules are 192B. Writes are tiny (1.5MB total).
// ---------------------------------------------------------------------------
template<int SW, int NC, int NOFF, int SCALE>
__device__ __forceinline__ void pool23_impl(const float* __restrict__ q,
                                            const float* __restrict__ k,
                                            const float* __restrict__ v,
                                            float* __restrict__ qg,
                                            float* __restrict__ kg,
                                            float* __restrict__ vg,
                                            unsigned int tid)
{
    const int BW = SW * 3;
    int ld = tid % 3;  tid /= 3;
    int nd = tid % NC; tid /= NC;
    int c  = tid % 8;  tid /= 8;
    int lw = tid % 3;  tid /= 3;
    int nw = tid % NC; tid /= NC;
    int lh = tid % 3;  tid /= 3;
    int nh = tid % NC; tid /= NC;
    int hd = tid % 2;  tid /= 2;
    int b  = tid % 4;  tid /= 4;
    int t  = (int)tid;

    const float* src = (t == 0) ? q : (t == 1) ? k : v;
    float*       dst = (t == 0) ? qg : (t == 1) ? kg : vg;

    int ch = SCALE * 16 + hd * 8 + c;
    int z0 = nh * BW + lh * SW;
    int y0 = nw * BW + lw * SW;
    int x0 = nd * BW + ld * SW;

    const float* base = src + ((((size_t)(b * 64 + ch) * 48 + z0) * 48 + y0) * 48 + x0);

    float m = -INFINITY;
    #pragma unroll
    for (int dz = 0; dz < SW; dz++) {
        #pragma unroll
        for (int dy = 0; dy < SW; dy++) {
            #pragma unroll
            for (int dx = 0; dx < SW; dx += 4) {
                float4 p = *(const float4*)(base + (dz * 48 + dy) * 48 + dx);
                m = fmaxf(m, fmaxf(fmaxf(p.x, p.y), fmaxf(p.z, p.w)));
            }
        }
    }

    int n = (nh * NC + nw) * NC + nd + NOFF;
    int l = (lh * 3 + lw) * 3 + ld;
    dst[((((size_t)(b * 2 + hd)) * NTOT + n) * 27 + l) * 8 + c] = m;
}

#define P23_B2 1296u   // scale 2: 331776/256
#define P23_B3 1458u   // +162   (scale 3)

__global__ void pool23_kernel(const float* __restrict__ q,
                              const float* __restrict__ k,
                              const float* __restrict__ v,
                              float* __restrict__ qg,
                              float* __restrict__ kg,
                              float* __restrict__ vg)
{
    unsigned int bid = blockIdx.x;
    if (bid < P23_B2) pool23_impl<4, 4, 4608, 2>(q, k, v, qg, kg, vg, bid * 256 + threadIdx.x);
    else              pool23_impl<8, 2, 4672, 3>(q, k, v, qg, kg, vg, (bid - P23_B2) * 256 + threadIdx.x);
}

// ---------------------------------------------------------------------------
// Attention, scales 2-3: 72 blocks x 8 windows (72 windows per bh, n>=4608).
// Same structure as the verified round-3 attn kernel; in-place into qg.
// ---------------------------------------------------------------------------
__global__ void attn23_kernel(float* qg,
                              const float* __restrict__ kg,
                              const float* __restrict__ vg,
                              const float* __restrict__ rpb)
{
    __shared__ float4 ks[432];
    __shared__ float4 vs[432];
    __shared__ float4 qs[432];
    __shared__ float tbl[250];

    int tid = threadIdx.x;
    int j  = blockIdx.x;          // 0..71
    int bh = j / 9;
    int wbase = bh * NTOT + 4608 + (j - bh * 9) * 8;
    int hd = bh & 1;

    for (int i = tid; i < 250; i += 256) tbl[i] = rpb[i];
    {
        const float4* kg4 = (const float4*)kg + (size_t)wbase * 54;
        const float4* vg4 = (const float4*)vg + (size_t)wbase * 54;
        const float4* qg4 = (const float4*)qg + (size_t)wbase * 54;
        for (int i = tid; i < 432; i += 256) {
            ks[i] = kg4[i];
            vs[i] = vg4[i];
            qs[i] = qg4[i];
        }
    }
    __syncthreads();

    int widx = tid >> 5;
    int m    = tid & 31;
    if (m < 27) {
        float4 q0 = qs[widx * 54 + m * 2];
        float4 q1 = qs[widx * 54 + m * 2 + 1];

        const float inv_scale = 0.35355339059327373f;
        float s[27], mx = -INFINITY;
        #pragma unroll
        for (int n = 0; n < 27; n++) {
            float4 k0 = ks[widx * 54 + n * 2];
            float4 k1 = ks[widx * 54 + n * 2 + 1];
            float acc = q0.x * k0.x + q0.y * k0.y + q0.z * k0.z + q0.w * k0.w
                      + q1.x * k1.x + q1.y * k1.y + q1.z * k1.z + q1.w * k1.w;
            acc *= inv_scale;
            s[n] = acc; mx = fmaxf(mx, acc);
        }
        float sum = 0.f;
        #pragma unroll
        for (int n = 0; n < 27; n++) { s[n] = __expf(s[n] - mx); sum += s[n]; }
        float inv = 1.f / sum;

        int mz = m / 9, my = (m / 3) % 3, mxx = m % 3;
        int mbase = ((mz + 2) * 5 + (my + 2)) * 5 + (mxx + 2);

        float4 a0 = make_float4(0.f, 0.f, 0.f, 0.f);
        float4 a1 = make_float4(0.f, 0.f, 0.f, 0.f);
        #pragma unroll
        for (int n = 0; n < 27; n++) {
            const int nz = n / 9, ny = (n / 3) % 3, nx = n % 3;
            const int nconst = (nz * 5 + ny) * 5 + nx;
            float wgt = s[n] * inv + tbl[(mbase - nconst) * 2 + hd];
            float4 v0 = vs[widx * 54 + n * 2];
            float4 v1 = vs[widx * 54 + n * 2 + 1];
            a0.x += wgt * v0.x; a0.y += wgt * v0.y; a0.z += wgt * v0.z; a0.w += wgt * v0.w;
            a1.x += wgt * v1.x; a1.y += wgt * v1.y; a1.z += wgt * v1.z; a1.w += wgt * v1.w;
        }
        qs[widx * 54 + m * 2]     = a0;
        qs[widx * 54 + m * 2 + 1] = a1;
    }
    __syncthreads();

    float4* og4 = (float4*)qg + (size_t)wbase * 54;
    for (int i = tid; i < 432; i += 256) og4[i] = qs[i];
}

// ---------------------------------------------------------------------------
// Scatter, scales 2-3: 4 outputs (one float4) per thread along x. Source
// attn region is ~0.5MB -> L2-resident taps; writes coalesced.
// ---------------------------------------------------------------------------
template<int SCALE>
__device__ __forceinline__ void scatter_impl(const float* __restrict__ attn,
                                             float* __restrict__ out,
                                             unsigned int tid)
{
    constexpr int BW   = (SCALE == 2) ? 12 : 24;
    constexpr int NC   = 16 >> SCALE;
    constexpr int NOFF = (SCALE == 2) ? 4608 : 4672;
    const float ST = 2.0f / (float)(BW - 1);

    int xq  = tid % 12; tid /= 12;
    int y   = tid % 48; tid /= 48;
    int z   = tid % 48; tid /= 48;
    int chi = tid % 16; tid /= 16;
    int b   = (int)tid;

    int hd = chi >> 3, c = chi & 7;

    int nh = z / BW, pz = z - nh * BW;
    int nw = y / BW, py = y - nw * BW;

    float fz = pz * ST; int z0 = (int)fz; if (z0 > 2) z0 = 2;
    float wz = fz - z0; int z1 = min(z0 + 1, 2);
    float fy = py * ST; int y0 = (int)fy; if (y0 > 2) y0 = 2;
    float wy = fy - y0; int y1 = min(y0 + 1, 2);

    float res[4];
    #pragma unroll
    for (int j = 0; j < 4; j++) {
        int x  = xq * 4 + j;
        int nd = x / BW, px = x - nd * BW;
        int n  = (nh * NC + nw) * NC + nd + NOFF;
        const float* a = attn + (((size_t)(b * 2 + hd) * NTOT + n) * 216) + c;
        float fx = px * ST; int x0 = (int)fx; if (x0 > 2) x0 = 2;
        float wx = fx - x0; int x1 = min(x0 + 1, 2);
        #define AT(iz, iy, ix) a[(((iz) * 3 + (iy)) * 3 + (ix)) * 8]
        float c00 = AT(z0, y0, x0) * (1.f - wx) + AT(z0, y0, x1) * wx;
        float c01 = AT(z0, y1, x0) * (1.f - wx) + AT(z0, y1, x1) * wx;
        float c10 = AT(z1, y0, x0) * (1.f - wx) + AT(z1, y0, x1) * wx;
        float c11 = AT(z1, y1, x0) * (1.f - wx) + AT(z1, y1, x1) * wx;
        float c0  = c00 * (1.f - wy) + c01 * wy;
        float c1  = c10 * (1.f - wy) + c11 * wy;
        res[j] = c0 * (1.f - wz) + c1 * wz;
        #undef AT
    }

    size_t ob = ((((size_t)(b * 64 + SCALE * 16 + chi) * 48 + z) * 48 + y) * 48) + xq * 4;
    *(float4*)(out + ob) = make_float4(res[0], res[1], res[2], res[3]);
}

#define SBLK 6912u  // 1769472/256 per scale

__global__ void scatter23_kernel(const float* __restrict__ attn,
                                 float* __restrict__ out)
{
    unsigned int bid = blockIdx.x;
    if (bid < SBLK) scatter_impl<2>(attn, out, bid * 256 + threadIdx.x);
    else            scatter_impl<3>(attn, out, (bid - SBLK) * 256 + threadIdx.x);
}

// ---------------------------------------------------------------------------
extern "C" void kernel_launch(void* const* d_in, const int* in_sizes, int n_in,
                              void* d_out, int out_size, void* d_ws, size_t ws_size,
                              hipStream_t stream)
{
    const float* q   = (const float*)d_in[0];
    const float* k   = (const float*)d_in[1];
    const float* v   = (const float*)d_in[2];
    const float* rpb = (const float*)d_in[3];
    float* out = (float*)d_out;

    float* qg = (float*)d_ws;
    float* kg = qg + GATHER_ELEMS;
    float* vg = kg + GATHER_ELEMS;

    // scales 0,1: fully fused (2048 + 512 blocks)
    fused01_kernel<<<2560, 512, 0, stream>>>(q, k, v, rpb, out);

    // scales 2,3: pool -> attn -> scatter (intermediates are L2-resident)
    pool23_kernel<<<P23_B3, 256, 0, stream>>>(q, k, v, qg, kg, vg);
    attn23_kernel<<<72, 256, 0, stream>>>(qg, kg, vg, rpb);
    scatter23_kernel<<<2 * SBLK, 256, 0, stream>>>(qg, out);
}